// Round 1
// baseline (640.321 us; speedup 1.0000x reference)
//
#include <hip/hip_runtime.h>
#include <hip/hip_bf16.h>
#include <stdint.h>

// WindowAttention: B_=4096 windows, N=64 tokens, C=192, H=6 heads, hd=32.
// One block per window, 4 waves; bf16 MFMA 16x16x32, fp32 accum, fp32 softmax.

#define NTOK 64
#define CDIM 192
#define NH 6
#define HD 32
#define LROW 200          // shorts per padded 192-wide row (400 B = 25*16, odd multiple of 16B)
#define SROW 72           // shorts per padded 64-wide row (144 B = 9*16)
#define WROWS 96          // weight chunk rows
#define NCHUNK 6

typedef __attribute__((ext_vector_type(4))) float f32x4;
typedef __attribute__((ext_vector_type(8))) short bf16x8;
typedef __attribute__((ext_vector_type(4))) short s16x4;

__device__ __forceinline__ short f2bf(float f) {
  union { float f; uint32_t u; } v; v.f = f;
  return (short)(uint16_t)((v.u + 0x7FFFu + ((v.u >> 16) & 1u)) >> 16);  // RNE
}

// Pre-convert weights fp32 -> bf16 into padded [rows][LROW] layout in workspace.
__global__ void wconv_kernel(const float* __restrict__ qkv_w,
                             const float* __restrict__ proj_w,
                             short* __restrict__ wsq,
                             short* __restrict__ wsp) {
  int r = blockIdx.x, t = threadIdx.x;  // 768 blocks x 192 threads
  if (r < 576) wsq[r * LROW + t] = f2bf(qkv_w[r * 192 + t]);
  else         wsp[(r - 576) * LROW + t] = f2bf(proj_w[(r - 576) * 192 + t]);
}

__global__ __launch_bounds__(256)
void winattn_kernel(const float* __restrict__ x, const float* __restrict__ mask,
                    const short* __restrict__ wsq, const short* __restrict__ wsp,
                    const float* __restrict__ qkv_b, const float* __restrict__ proj_b,
                    float* __restrict__ out) {
  extern __shared__ short lds[];
  short* xb  = lds;                      // [64][LROW] bf16 x; later aliased as attn-out o
  short* wch = xb + 64 * LROW;           // [96][LROW] weight chunk
  short* qs  = wch + WROWS * LROW;       // [64][LROW] q (all heads)
  short* ks  = qs + 64 * LROW;           // [64][LROW] k (all heads)
  short* vt  = ks + 64 * LROW;           // [192][SROW] v transposed: vt[ch][token]
  short* ps  = vt + 192 * SROW;          // [64][SROW] probs bf16
  // total = (64+96+64+64)*200 + 192*72 + 64*72 = 76032 shorts = 152064 B

  const int b    = blockIdx.x;
  const int tid  = threadIdx.x;
  const int lane = tid & 63;
  const int l16  = lane & 15;            // MFMA frag row/col within tile
  const int g4   = lane >> 4;            // k-slice group 0..3
  const int m0   = (tid >> 6) * 16;      // wave's token-row base

  // ---------------- stage x: fp32 -> bf16 LDS ----------------
  const float* xg = x + (size_t)b * (NTOK * CDIM);
  #pragma unroll
  for (int j = 0; j < 12; ++j) {
    int i4 = tid + j * 256;                      // 3072 float4 total
    const float4 v = reinterpret_cast<const float4*>(xg)[i4];
    int e = i4 * 4, n = e / CDIM, c = e % CDIM;
    s16x4 o; o[0] = f2bf(v.x); o[1] = f2bf(v.y); o[2] = f2bf(v.z); o[3] = f2bf(v.w);
    *reinterpret_cast<s16x4*>(xb + n * LROW + c) = o;
  }

  // ---------------- QKV projection: qkv = x @ W^T + b ----------------
  for (int chk = 0; chk < NCHUNK; ++chk) {
    if (chk) __syncthreads();                    // protect wch overwrite
    {
      const uint4* src = reinterpret_cast<const uint4*>(wsq + chk * WROWS * LROW);
      uint4* dst = reinterpret_cast<uint4*>(wch);
      for (int i = tid; i < WROWS * LROW / 8; i += 256) dst[i] = src[i];
    }
    __syncthreads();                             // wch (and xb on chk==0) ready

    bf16x8 af[6];
    #pragma unroll
    for (int ksi = 0; ksi < 6; ++ksi)
      af[ksi] = *reinterpret_cast<const bf16x8*>(xb + (m0 + l16) * LROW + ksi * 32 + g4 * 8);

    const int which = chk >> 1;                  // 0=q, 1=k, 2=v (uniform per chunk)
    #pragma unroll
    for (int ct = 0; ct < 6; ++ct) {
      f32x4 acc = {0.f, 0.f, 0.f, 0.f};
      #pragma unroll
      for (int ksi = 0; ksi < 6; ++ksi) {
        bf16x8 bf = *reinterpret_cast<const bf16x8*>(wch + (ct * 16 + l16) * LROW + ksi * 32 + g4 * 8);
        acc = __builtin_amdgcn_mfma_f32_16x16x32_bf16(af[ksi], bf, acc, 0, 0, 0);
      }
      int gc = chk * WROWS + ct * 16 + l16;      // global output channel 0..575
      float bias = qkv_b[gc];
      int cc = gc - which * CDIM;                // channel within q/k/v
      #pragma unroll
      for (int i = 0; i < 4; ++i) {
        int r = m0 + g4 * 4 + i;                 // D row = token
        short hv = f2bf(acc[i] + bias);
        if (which == 0)      qs[r * LROW + cc] = hv;
        else if (which == 1) ks[r * LROW + cc] = hv;
        else                 vt[cc * SROW + r] = hv;   // transpose V
      }
    }
  }
  __syncthreads();   // q/k/vt visible to all waves; all xb reads done (o aliases xb)

  // ---------------- attention per head (barrier-free across heads) ----------------
  const float scale = 0.17677669529663687f;      // 32^-0.5
  const float* mrow = mask + (size_t)b * (NTOK * NTOK);
  for (int h = 0; h < NH; ++h) {
    const int hc = h * HD;
    // S = (q @ k^T) * scale + mask ; rows m0..m0+15
    bf16x8 aq = *reinterpret_cast<const bf16x8*>(qs + (m0 + l16) * LROW + hc + g4 * 8);
    float pr[4][4];
    float rmax[4] = {-1e30f, -1e30f, -1e30f, -1e30f};
    #pragma unroll
    for (int ct = 0; ct < 4; ++ct) {
      bf16x8 bk = *reinterpret_cast<const bf16x8*>(ks + (ct * 16 + l16) * LROW + hc + g4 * 8);
      f32x4 z = {0.f, 0.f, 0.f, 0.f};
      f32x4 sc = __builtin_amdgcn_mfma_f32_16x16x32_bf16(aq, bk, z, 0, 0, 0);
      #pragma unroll
      for (int i = 0; i < 4; ++i) {
        int r = m0 + g4 * 4 + i, cn = ct * 16 + l16;
        float s = sc[i] * scale + mrow[r * 64 + cn];
        pr[ct][i] = s;
        rmax[i] = fmaxf(rmax[i], s);
      }
    }
    // row softmax: each row's 64 values live in one 16-lane group (4 per lane)
    #pragma unroll
    for (int d = 1; d < 16; d <<= 1)
      #pragma unroll
      for (int i = 0; i < 4; ++i)
        rmax[i] = fmaxf(rmax[i], __shfl_xor(rmax[i], d));
    float rsum[4] = {0.f, 0.f, 0.f, 0.f};
    #pragma unroll
    for (int ct = 0; ct < 4; ++ct)
      #pragma unroll
      for (int i = 0; i < 4; ++i) {
        float e = __expf(pr[ct][i] - rmax[i]);
        pr[ct][i] = e; rsum[i] += e;
      }
    #pragma unroll
    for (int d = 1; d < 16; d <<= 1)
      #pragma unroll
      for (int i = 0; i < 4; ++i)
        rsum[i] += __shfl_xor(rsum[i], d);
    float rinv[4];
    #pragma unroll
    for (int i = 0; i < 4; ++i) rinv[i] = 1.f / rsum[i];
    #pragma unroll
    for (int ct = 0; ct < 4; ++ct)
      #pragma unroll
      for (int i = 0; i < 4; ++i)
        ps[(m0 + g4 * 4 + i) * SROW + ct * 16 + l16] = f2bf(pr[ct][i] * rinv[i]);

    // PV: out_h = P @ V  (A=P rows m0.., B=V via vt so k(=token) is contiguous)
    bf16x8 ap0 = *reinterpret_cast<const bf16x8*>(ps + (m0 + l16) * SROW + g4 * 8);
    bf16x8 ap1 = *reinterpret_cast<const bf16x8*>(ps + (m0 + l16) * SROW + 32 + g4 * 8);
    #pragma unroll
    for (int ct = 0; ct < 2; ++ct) {
      const short* vb = vt + (hc + ct * 16 + l16) * SROW;
      bf16x8 bv0 = *reinterpret_cast<const bf16x8*>(vb + g4 * 8);
      bf16x8 bv1 = *reinterpret_cast<const bf16x8*>(vb + 32 + g4 * 8);
      f32x4 acc = {0.f, 0.f, 0.f, 0.f};
      acc = __builtin_amdgcn_mfma_f32_16x16x32_bf16(ap0, bv0, acc, 0, 0, 0);
      acc = __builtin_amdgcn_mfma_f32_16x16x32_bf16(ap1, bv1, acc, 0, 0, 0);
      #pragma unroll
      for (int i = 0; i < 4; ++i)
        xb[(m0 + g4 * 4 + i) * LROW + hc + ct * 16 + l16] = f2bf(acc[i]);  // o into xb
    }
  }

  // ---------------- output projection: out = o @ proj_w^T + b ----------------
  float* og = out + (size_t)b * (NTOK * CDIM);
  for (int pc = 0; pc < 2; ++pc) {
    __syncthreads();                             // all waves done with heads / prev chunk
    {
      const uint4* src = reinterpret_cast<const uint4*>(wsp + pc * WROWS * LROW);
      uint4* dst = reinterpret_cast<uint4*>(wch);
      for (int i = tid; i < WROWS * LROW / 8; i += 256) dst[i] = src[i];
    }
    __syncthreads();
    bf16x8 af[6];
    #pragma unroll
    for (int ksi = 0; ksi < 6; ++ksi)
      af[ksi] = *reinterpret_cast<const bf16x8*>(xb + (m0 + l16) * LROW + ksi * 32 + g4 * 8);
    #pragma unroll
    for (int ct = 0; ct < 6; ++ct) {
      f32x4 acc = {0.f, 0.f, 0.f, 0.f};
      #pragma unroll
      for (int ksi = 0; ksi < 6; ++ksi) {
        bf16x8 bf = *reinterpret_cast<const bf16x8*>(wch + (ct * 16 + l16) * LROW + ksi * 32 + g4 * 8);
        acc = __builtin_amdgcn_mfma_f32_16x16x32_bf16(af[ksi], bf, acc, 0, 0, 0);
      }
      int c = pc * WROWS + ct * 16 + l16;
      float bias = proj_b[c];
      #pragma unroll
      for (int i = 0; i < 4; ++i)
        og[(m0 + g4 * 4 + i) * CDIM + c] = acc[i] + bias;
    }
  }
}

extern "C" void kernel_launch(void* const* d_in, const int* in_sizes, int n_in,
                              void* d_out, int out_size, void* d_ws, size_t ws_size,
                              hipStream_t stream) {
  const float* x      = (const float*)d_in[0];
  const float* mask   = (const float*)d_in[1];
  const float* qkv_w  = (const float*)d_in[2];
  const float* qkv_b  = (const float*)d_in[3];
  const float* proj_w = (const float*)d_in[4];
  const float* proj_b = (const float*)d_in[5];
  float* out = (float*)d_out;

  short* wsq = (short*)d_ws;               // [576][LROW] bf16
  short* wsp = wsq + 576 * LROW;           // [192][LROW] bf16  (307200 B total)

  wconv_kernel<<<768, 192, 0, stream>>>(qkv_w, proj_w, wsq, wsp);

  const int lds_bytes = 76032 * 2;         // 152064
  (void)hipFuncSetAttribute((const void*)winattn_kernel,
                            hipFuncAttributeMaxDynamicSharedMemorySize, lds_bytes);
  winattn_kernel<<<4096, 256, lds_bytes, stream>>>(x, mask, wsq, wsp, qkv_b, proj_b, out);
}

// Round 2
// 561.648 us; speedup vs baseline: 1.1401x; 1.1401x over previous
//
#include <hip/hip_runtime.h>
#include <stdint.h>

// WindowAttention: B_=4096 windows, N=64 tokens, C=192, H=6 heads, hd=32.
// One block per window, 4 waves (wave w owns token rows 16w..16w+15).
// bf16 MFMA 16x16x32, fp32 accum. S^T trick: softmax fully in-register.
// LDS = qs/o (25.6K) + kh (5.1K) + vth (4.6K) = 35.3 KB -> 4 blocks/CU.

#define NTOK 64
#define CDIM 192
#define LROW 200          // qs row stride (shorts): 400 B = 25*16 (odd mult of 16B)
#define KROW 40           // kh row stride: 80 B = 5*16
#define VROW 72           // vth row stride: 144 B = 9*16

typedef __attribute__((ext_vector_type(4))) float f32x4;
typedef __attribute__((ext_vector_type(8))) short bf16x8;

__device__ __forceinline__ short f2bf(float f) {
  union { float f; uint32_t u; } v; v.f = f;
  return (short)(uint16_t)((v.u + 0x7FFFu + ((v.u >> 16) & 1u)) >> 16);  // RNE
}
__device__ __forceinline__ uint32_t pack2(float a, float b) {
  return (uint32_t)(uint16_t)f2bf(a) | ((uint32_t)(uint16_t)f2bf(b) << 16);
}

// Pre-convert weights fp32 -> bf16, packed [rows][192].
__global__ void wconv_kernel(const float* __restrict__ qkv_w,
                             const float* __restrict__ proj_w,
                             short* __restrict__ wsq, short* __restrict__ wsp) {
  int r = blockIdx.x, t = threadIdx.x;  // 768 x 192
  if (r < 576) wsq[r * CDIM + t] = f2bf(qkv_w[r * CDIM + t]);
  else         wsp[(r - 576) * CDIM + t] = f2bf(proj_w[(r - 576) * CDIM + t]);
}

__global__ __launch_bounds__(256, 4)
void winattn_kernel(const float* __restrict__ x, const float* __restrict__ mask,
                    const short* __restrict__ wsq, const short* __restrict__ wsp,
                    const float* __restrict__ qkv_b, const float* __restrict__ proj_b,
                    float* __restrict__ out) {
  __shared__ short qs[NTOK * LROW];   // q (pre-scaled) all heads; o overwrites per head
  __shared__ short kh[NTOK * KROW];   // current head's k [token][32]
  __shared__ short vth[32 * VROW];    // current head's v^T [ch][token]

  const int b    = blockIdx.x;
  const int tid  = threadIdx.x;
  const int lane = tid & 63;
  const int l16  = lane & 15;
  const int g4   = lane >> 4;
  const int m0   = (tid >> 6) * 16;          // wave's token base
  const float scale = 0.17677669529663687f;  // 32^-0.5

  // ---- A-fragments: x row m0+l16, fp32->bf16, loaded ONCE, reused for q/k/v GEMMs ----
  const float* xr = x + (size_t)b * (NTOK * CDIM) + (m0 + l16) * CDIM;
  bf16x8 af[6];
  #pragma unroll
  for (int ksi = 0; ksi < 6; ++ksi) {
    const float4 v0 = *reinterpret_cast<const float4*>(xr + ksi * 32 + g4 * 8);
    const float4 v1 = *reinterpret_cast<const float4*>(xr + ksi * 32 + g4 * 8 + 4);
    bf16x8 t;
    t[0] = f2bf(v0.x); t[1] = f2bf(v0.y); t[2] = f2bf(v0.z); t[3] = f2bf(v0.w);
    t[4] = f2bf(v1.x); t[5] = f2bf(v1.y); t[6] = f2bf(v1.z); t[7] = f2bf(v1.w);
    af[ksi] = t;
  }

  // ---- q-GEMM (cols 0..191), scale folded in; q is wave-private in qs ----
  #pragma unroll 2
  for (int cp = 0; cp < 6; ++cp) {           // pairs of 16-col tiles for ILP
    const int wr0 = (cp * 2) * 16 + l16, wr1 = (cp * 2 + 1) * 16 + l16;
    f32x4 a0 = {0,0,0,0}, a1 = {0,0,0,0};
    #pragma unroll
    for (int ksi = 0; ksi < 6; ++ksi) {
      bf16x8 b0 = *reinterpret_cast<const bf16x8*>(wsq + wr0 * CDIM + ksi * 32 + g4 * 8);
      bf16x8 b1 = *reinterpret_cast<const bf16x8*>(wsq + wr1 * CDIM + ksi * 32 + g4 * 8);
      a0 = __builtin_amdgcn_mfma_f32_16x16x32_bf16(af[ksi], b0, a0, 0, 0, 0);
      a1 = __builtin_amdgcn_mfma_f32_16x16x32_bf16(af[ksi], b1, a1, 0, 0, 0);
    }
    float bi0 = qkv_b[wr0], bi1 = qkv_b[wr1];
    #pragma unroll
    for (int i = 0; i < 4; ++i) {
      int r = m0 + g4 * 4 + i;
      qs[r * LROW + wr0] = f2bf((a0[i] + bi0) * scale);
      qs[r * LROW + wr1] = f2bf((a1[i] + bi1) * scale);
    }
  }

  // ---- per-head: kv-GEMM -> S^T -> in-register softmax -> shfl-permute -> PV ----
  const float* mrowl = mask + (size_t)b * (NTOK * NTOK) + (m0 + l16) * NTOK;
  for (int h = 0; h < 6; ++h) {
    const int hc = h * 32;
    __syncthreads();                         // prev head's kh/vth reads done

    // k_h and v_h (2 col-tiles each, 4 independent acc chains)
    {
      const int c0 = l16, c1 = 16 + l16;
      f32x4 k0 = {0,0,0,0}, k1 = {0,0,0,0}, v0 = {0,0,0,0}, v1 = {0,0,0,0};
      const int kw0 = 192 + hc + c0, kw1 = 192 + hc + c1;
      const int vw0 = 384 + hc + c0, vw1 = 384 + hc + c1;
      #pragma unroll
      for (int ksi = 0; ksi < 6; ++ksi) {
        const int co = ksi * 32 + g4 * 8;
        bf16x8 bk0 = *reinterpret_cast<const bf16x8*>(wsq + kw0 * CDIM + co);
        bf16x8 bk1 = *reinterpret_cast<const bf16x8*>(wsq + kw1 * CDIM + co);
        bf16x8 bv0 = *reinterpret_cast<const bf16x8*>(wsq + vw0 * CDIM + co);
        bf16x8 bv1 = *reinterpret_cast<const bf16x8*>(wsq + vw1 * CDIM + co);
        k0 = __builtin_amdgcn_mfma_f32_16x16x32_bf16(af[ksi], bk0, k0, 0, 0, 0);
        k1 = __builtin_amdgcn_mfma_f32_16x16x32_bf16(af[ksi], bk1, k1, 0, 0, 0);
        v0 = __builtin_amdgcn_mfma_f32_16x16x32_bf16(af[ksi], bv0, v0, 0, 0, 0);
        v1 = __builtin_amdgcn_mfma_f32_16x16x32_bf16(af[ksi], bv1, v1, 0, 0, 0);
      }
      float kb0 = qkv_b[kw0], kb1 = qkv_b[kw1], vb0 = qkv_b[vw0], vb1 = qkv_b[vw1];
      #pragma unroll
      for (int i = 0; i < 4; ++i) {
        int r = m0 + g4 * 4 + i;
        kh[r * KROW + c0] = f2bf(k0[i] + kb0);
        kh[r * KROW + c1] = f2bf(k1[i] + kb1);
        vth[c0 * VROW + r] = f2bf(v0[i] + vb0);   // transpose v
        vth[c1 * VROW + r] = f2bf(v1[i] + vb1);
      }
    }
    __syncthreads();                         // kh/vth complete

    // S^T = mfma(K, Q): lane holds S[qt=m0+l16][kt=16rt+4g4+i], all same qt
    bf16x8 aq = *reinterpret_cast<const bf16x8*>(qs + (m0 + l16) * LROW + hc + g4 * 8);
    float p[4][4];
    float rmax = -1e30f;
    #pragma unroll
    for (int rt = 0; rt < 4; ++rt) {
      bf16x8 bk = *reinterpret_cast<const bf16x8*>(kh + (rt * 16 + l16) * KROW + g4 * 8);
      f32x4 z = {0,0,0,0};
      f32x4 s = __builtin_amdgcn_mfma_f32_16x16x32_bf16(bk, aq, z, 0, 0, 0);
      const float4 mv = *reinterpret_cast<const float4*>(mrowl + 16 * rt + 4 * g4);
      p[rt][0] = s[0] + mv.x; p[rt][1] = s[1] + mv.y;
      p[rt][2] = s[2] + mv.z; p[rt][3] = s[3] + mv.w;
      #pragma unroll
      for (int i = 0; i < 4; ++i) rmax = fmaxf(rmax, p[rt][i]);
    }
    rmax = fmaxf(rmax, __shfl_xor(rmax, 16));
    rmax = fmaxf(rmax, __shfl_xor(rmax, 32));
    float rsum = 0.f;
    #pragma unroll
    for (int rt = 0; rt < 4; ++rt)
      #pragma unroll
      for (int i = 0; i < 4; ++i) { p[rt][i] = __expf(p[rt][i] - rmax); rsum += p[rt][i]; }
    rsum += __shfl_xor(rsum, 16);
    rsum += __shfl_xor(rsum, 32);
    const float rinv = 1.f / rsum;

    uint32_t wpk[4][2];
    #pragma unroll
    for (int rt = 0; rt < 4; ++rt) {
      wpk[rt][0] = pack2(p[rt][0] * rinv, p[rt][1] * rinv);
      wpk[rt][1] = pack2(p[rt][2] * rinv, p[rt][3] * rinv);
    }
    // in-register transpose: P^T (D-layout) -> PV A-fragments (kt-contiguous)
    const int rsel = g4 >> 1;
    uint32_t a0w[4], a1w[4];
    #pragma unroll
    for (int ww = 0; ww < 4; ++ww) {
      const int srcl = l16 + (((2 * g4 + (ww >> 1)) & 3) << 4);
      uint32_t c00 = __shfl(wpk[0][ww & 1], srcl);
      uint32_t c01 = __shfl(wpk[1][ww & 1], srcl);
      uint32_t c10 = __shfl(wpk[2][ww & 1], srcl);
      uint32_t c11 = __shfl(wpk[3][ww & 1], srcl);
      a0w[ww] = rsel ? c01 : c00;
      a1w[ww] = rsel ? c11 : c10;
    }
    bf16x8 ap0 = *reinterpret_cast<const bf16x8*>(a0w);
    bf16x8 ap1 = *reinterpret_cast<const bf16x8*>(a1w);

    // PV: o[qt][hc+ct*16+l16]; writes into qs (head h cols already consumed)
    #pragma unroll
    for (int ct = 0; ct < 2; ++ct) {
      const short* vb = vth + (ct * 16 + l16) * VROW;
      bf16x8 bv0 = *reinterpret_cast<const bf16x8*>(vb + g4 * 8);
      bf16x8 bv1 = *reinterpret_cast<const bf16x8*>(vb + 32 + g4 * 8);
      f32x4 acc = {0,0,0,0};
      acc = __builtin_amdgcn_mfma_f32_16x16x32_bf16(ap0, bv0, acc, 0, 0, 0);
      acc = __builtin_amdgcn_mfma_f32_16x16x32_bf16(ap1, bv1, acc, 0, 0, 0);
      #pragma unroll
      for (int i = 0; i < 4; ++i)
        qs[(m0 + g4 * 4 + i) * LROW + hc + ct * 16 + l16] = f2bf(acc[i]);
    }
  }

  // ---- proj (o is wave-private in qs: no barrier needed) ----
  bf16x8 of[6];
  #pragma unroll
  for (int ksi = 0; ksi < 6; ++ksi)
    of[ksi] = *reinterpret_cast<const bf16x8*>(qs + (m0 + l16) * LROW + ksi * 32 + g4 * 8);
  float* og = out + (size_t)b * (NTOK * CDIM);
  #pragma unroll 2
  for (int cp = 0; cp < 6; ++cp) {
    const int wr0 = (cp * 2) * 16 + l16, wr1 = (cp * 2 + 1) * 16 + l16;
    f32x4 a0 = {0,0,0,0}, a1 = {0,0,0,0};
    #pragma unroll
    for (int ksi = 0; ksi < 6; ++ksi) {
      bf16x8 b0 = *reinterpret_cast<const bf16x8*>(wsp + wr0 * CDIM + ksi * 32 + g4 * 8);
      bf16x8 b1 = *reinterpret_cast<const bf16x8*>(wsp + wr1 * CDIM + ksi * 32 + g4 * 8);
      a0 = __builtin_amdgcn_mfma_f32_16x16x32_bf16(of[ksi], b0, a0, 0, 0, 0);
      a1 = __builtin_amdgcn_mfma_f32_16x16x32_bf16(of[ksi], b1, a1, 0, 0, 0);
    }
    float bi0 = proj_b[wr0], bi1 = proj_b[wr1];
    #pragma unroll
    for (int i = 0; i < 4; ++i) {
      int r = m0 + g4 * 4 + i;
      og[r * CDIM + wr0] = a0[i] + bi0;
      og[r * CDIM + wr1] = a1[i] + bi1;
    }
  }
}

extern "C" void kernel_launch(void* const* d_in, const int* in_sizes, int n_in,
                              void* d_out, int out_size, void* d_ws, size_t ws_size,
                              hipStream_t stream) {
  const float* x      = (const float*)d_in[0];
  const float* mask   = (const float*)d_in[1];
  const float* qkv_w  = (const float*)d_in[2];
  const float* qkv_b  = (const float*)d_in[3];
  const float* proj_w = (const float*)d_in[4];
  const float* proj_b = (const float*)d_in[5];
  float* out = (float*)d_out;

  short* wsq = (short*)d_ws;             // [576][192] bf16
  short* wsp = wsq + 576 * CDIM;         // [192][192] bf16

  wconv_kernel<<<768, 192, 0, stream>>>(qkv_w, proj_w, wsq, wsp);
  winattn_kernel<<<4096, 256, 0, stream>>>(x, mask, wsq, wsp, qkv_b, proj_b, out);
}

// Round 3
// 273.386 us; speedup vs baseline: 2.3422x; 2.0544x over previous
//
#include <hip/hip_runtime.h>
#include <stdint.h>

// WindowAttention: B_=4096 windows, N=64 tokens, C=192, H=6 heads, hd=32.
// One block per window, 4 waves (wave w owns token rows 16w..16w+15).
// All weights staged through one 25.6KB LDS buffer; q/o live in registers via
// shfl transposes (same lane algebra as the validated P-permute). bf16 MFMA.

#define NTOK 64
#define CDIM 192
#define LROW 200          // wbuf row stride (shorts): 400 B = 25*16
#define KROW 40           // kh row stride: 80 B = 5*16
#define VROW 72           // vth row stride: 144 B = 9*16

typedef __attribute__((ext_vector_type(4))) float f32x4;
typedef __attribute__((ext_vector_type(8))) short bf16x8;

__device__ __forceinline__ short f2bf(float f) {
  union { float f; uint32_t u; } v; v.f = f;
  return (short)(uint16_t)((v.u + 0x7FFFu + ((v.u >> 16) & 1u)) >> 16);  // RNE
}
__device__ __forceinline__ uint32_t pack2(float a, float b) {
  return (uint32_t)(uint16_t)f2bf(a) | ((uint32_t)(uint16_t)f2bf(b) << 16);
}

// Cross-lane transpose: build a bf16x8 A/B-fragment from two candidate packed
// uint32 pairs (tile0 = A0,A1; tile1 = B0,B1), selecting by hiSel after shfl.
// Identical structure to the round-2-validated P permute.
__device__ __forceinline__ bf16x8 xpose(uint32_t A0, uint32_t A1,
                                        uint32_t B0, uint32_t B1,
                                        int s0, int s1, int hiSel) {
  uint32_t w[4];
  uint32_t a, b;
  a = (uint32_t)__shfl((int)A0, s0); b = (uint32_t)__shfl((int)B0, s0); w[0] = hiSel ? b : a;
  a = (uint32_t)__shfl((int)A1, s0); b = (uint32_t)__shfl((int)B1, s0); w[1] = hiSel ? b : a;
  a = (uint32_t)__shfl((int)A0, s1); b = (uint32_t)__shfl((int)B0, s1); w[2] = hiSel ? b : a;
  a = (uint32_t)__shfl((int)A1, s1); b = (uint32_t)__shfl((int)B1, s1); w[3] = hiSel ? b : a;
  return *reinterpret_cast<bf16x8*>(w);
}

// Pre-convert weights fp32 -> bf16, packed [rows][192].
__global__ void wconv_kernel(const float* __restrict__ qkv_w,
                             const float* __restrict__ proj_w,
                             short* __restrict__ wsq, short* __restrict__ wsp) {
  int r = blockIdx.x, t = threadIdx.x;  // 768 x 192
  if (r < 576) wsq[r * CDIM + t] = f2bf(qkv_w[r * CDIM + t]);
  else         wsp[(r - 576) * CDIM + t] = f2bf(proj_w[(r - 576) * CDIM + t]);
}

__device__ __forceinline__ void stage64(short* __restrict__ dst,
                                        const short* __restrict__ src, int tid) {
  const uint4* s = reinterpret_cast<const uint4*>(src);   // 64 rows x 24 uint4
  #pragma unroll
  for (int it = 0; it < 6; ++it) {
    int idx = tid + it * 256;                 // 0..1535
    int row = idx / 24, c8 = idx - row * 24;
    *reinterpret_cast<uint4*>(dst + row * LROW + c8 * 8) = s[idx];
  }
}

__global__ __launch_bounds__(256, 4)
void winattn_kernel(const float* __restrict__ x, const float* __restrict__ mask,
                    const short* __restrict__ wsq, const short* __restrict__ wsp,
                    const float* __restrict__ qkv_b, const float* __restrict__ proj_b,
                    float* __restrict__ out) {
  __shared__ __align__(16) short wbuf[64 * LROW];  // weight chunk (64 out-cols x 192)
  __shared__ __align__(16) short kh[NTOK * KROW];  // current head k [tok][32]
  __shared__ __align__(16) short vth[32 * VROW];   // current head v^T [ch][tok]

  const int b    = blockIdx.x;
  const int tid  = threadIdx.x;
  const int lane = tid & 63;
  const int l16  = lane & 15;
  const int g4   = lane >> 4;
  const int m0   = (tid >> 6) * 16;
  const float scale = 0.17677669529663687f;  // 32^-0.5
  const int s0 = (((2 * g4) & 3) << 4) + l16;
  const int s1 = (((2 * g4 + 1) & 3) << 4) + l16;
  const int hiSel = g4 >> 1;

  // ---- x A-fragments (also valid as B-operand), loaded once ----
  const float* xr = x + (size_t)b * (NTOK * CDIM) + (m0 + l16) * CDIM;
  bf16x8 af[6];
  #pragma unroll
  for (int ks = 0; ks < 6; ++ks) {
    const float4 v0 = *reinterpret_cast<const float4*>(xr + ks * 32 + g4 * 8);
    const float4 v1 = *reinterpret_cast<const float4*>(xr + ks * 32 + g4 * 8 + 4);
    bf16x8 t;
    t[0] = f2bf(v0.x); t[1] = f2bf(v0.y); t[2] = f2bf(v0.z); t[3] = f2bf(v0.w);
    t[4] = f2bf(v1.x); t[5] = f2bf(v1.y); t[6] = f2bf(v1.z); t[7] = f2bf(v1.w);
    af[ks] = t;
  }

  // ---- q phase: 3 chunks of 64 cols; q^T = mfma(Wq, x) -> aq[] in registers ----
  bf16x8 aq[6];
  #pragma unroll
  for (int c = 0; c < 3; ++c) {
    if (c) __syncthreads();                  // prev chunk's wbuf reads done
    stage64(wbuf, wsq + (size_t)(64 * c) * CDIM, tid);
    __syncthreads();
    uint32_t u[4][2];
    #pragma unroll
    for (int lct = 0; lct < 4; ++lct) {
      f32x4 acc = {0.f, 0.f, 0.f, 0.f};
      #pragma unroll
      for (int ks = 0; ks < 6; ++ks) {
        bf16x8 wf = *reinterpret_cast<const bf16x8*>(wbuf + (lct * 16 + l16) * LROW + ks * 32 + g4 * 8);
        acc = __builtin_amdgcn_mfma_f32_16x16x32_bf16(wf, af[ks], acc, 0, 0, 0);
      }
      const float4 bq = *reinterpret_cast<const float4*>(qkv_b + 64 * c + 16 * lct + 4 * g4);
      u[lct][0] = pack2((acc[0] + bq.x) * scale, (acc[1] + bq.y) * scale);
      u[lct][1] = pack2((acc[2] + bq.z) * scale, (acc[3] + bq.w) * scale);
    }
    aq[2 * c]     = xpose(u[0][0], u[0][1], u[1][0], u[1][1], s0, s1, hiSel);
    aq[2 * c + 1] = xpose(u[2][0], u[2][1], u[3][0], u[3][1], s0, s1, hiSel);
  }

  // ---- per-head loop ----
  const float* mrowl = mask + (size_t)b * (NTOK * NTOK) + (m0 + l16) * NTOK;
  bf16x8 of[6];
  #pragma unroll
  for (int h = 0; h < 6; ++h) {
    __syncthreads();                         // prev head's kh/vth reads + wbuf reads done
    {
      const uint4* sk = reinterpret_cast<const uint4*>(wsq + (size_t)(192 + 32 * h) * CDIM);
      const uint4* sv = reinterpret_cast<const uint4*>(wsq + (size_t)(384 + 32 * h) * CDIM);
      #pragma unroll
      for (int it = 0; it < 3; ++it) {
        int idx = tid + it * 256;            // 0..767 (32 rows x 24 uint4)
        int row = idx / 24, c8 = idx - row * 24;
        *reinterpret_cast<uint4*>(wbuf + row * LROW + c8 * 8) = sk[idx];
        *reinterpret_cast<uint4*>(wbuf + (32 + row) * LROW + c8 * 8) = sv[idx];
      }
    }
    __syncthreads();                         // wbuf(k,v slices) ready

    // k^T = mfma(Wk, x): lane holds 4 chs of its own token -> uint2 into kh[tok][ch]
    #pragma unroll
    for (int lct = 0; lct < 2; ++lct) {
      f32x4 acc = {0.f, 0.f, 0.f, 0.f};
      #pragma unroll
      for (int ks = 0; ks < 6; ++ks) {
        bf16x8 wf = *reinterpret_cast<const bf16x8*>(wbuf + (lct * 16 + l16) * LROW + ks * 32 + g4 * 8);
        acc = __builtin_amdgcn_mfma_f32_16x16x32_bf16(wf, af[ks], acc, 0, 0, 0);
      }
      const float4 bk4 = *reinterpret_cast<const float4*>(qkv_b + 192 + 32 * h + 16 * lct + 4 * g4);
      uint2 kw;
      kw.x = pack2(acc[0] + bk4.x, acc[1] + bk4.y);
      kw.y = pack2(acc[2] + bk4.z, acc[3] + bk4.w);
      *reinterpret_cast<uint2*>(kh + (m0 + l16) * KROW + 16 * lct + 4 * g4) = kw;
    }
    // v = mfma(x, Wv): lane holds 4 toks of one ch -> uint2 into vth[ch][tok]
    #pragma unroll
    for (int lct = 0; lct < 2; ++lct) {
      f32x4 acc = {0.f, 0.f, 0.f, 0.f};
      #pragma unroll
      for (int ks = 0; ks < 6; ++ks) {
        bf16x8 wf = *reinterpret_cast<const bf16x8*>(wbuf + (32 + lct * 16 + l16) * LROW + ks * 32 + g4 * 8);
        acc = __builtin_amdgcn_mfma_f32_16x16x32_bf16(af[ks], wf, acc, 0, 0, 0);
      }
      const float bv = qkv_b[384 + 32 * h + 16 * lct + l16];
      uint2 vw;
      vw.x = pack2(acc[0] + bv, acc[1] + bv);
      vw.y = pack2(acc[2] + bv, acc[3] + bv);
      *reinterpret_cast<uint2*>(vth + (16 * lct + l16) * VROW + m0 + 4 * g4) = vw;
    }
    __syncthreads();                         // kh/vth ready

    // S^T = mfma(K, q): lane = its own query token, 16 scores in-register
    float p[4][4];
    float rmax = -1e30f;
    #pragma unroll
    for (int rt = 0; rt < 4; ++rt) {
      bf16x8 bk = *reinterpret_cast<const bf16x8*>(kh + (rt * 16 + l16) * KROW + g4 * 8);
      f32x4 z = {0.f, 0.f, 0.f, 0.f};
      f32x4 s = __builtin_amdgcn_mfma_f32_16x16x32_bf16(bk, aq[h], z, 0, 0, 0);
      const float4 mv = *reinterpret_cast<const float4*>(mrowl + 16 * rt + 4 * g4);
      p[rt][0] = s[0] + mv.x; p[rt][1] = s[1] + mv.y;
      p[rt][2] = s[2] + mv.z; p[rt][3] = s[3] + mv.w;
      #pragma unroll
      for (int i = 0; i < 4; ++i) rmax = fmaxf(rmax, p[rt][i]);
    }
    rmax = fmaxf(rmax, __shfl_xor(rmax, 16));
    rmax = fmaxf(rmax, __shfl_xor(rmax, 32));
    float rsum = 0.f;
    #pragma unroll
    for (int rt = 0; rt < 4; ++rt)
      #pragma unroll
      for (int i = 0; i < 4; ++i) { p[rt][i] = __expf(p[rt][i] - rmax); rsum += p[rt][i]; }
    rsum += __shfl_xor(rsum, 16);
    rsum += __shfl_xor(rsum, 32);
    const float rinv = 1.f / rsum;

    uint32_t wpk[4][2];
    #pragma unroll
    for (int rt = 0; rt < 4; ++rt) {
      wpk[rt][0] = pack2(p[rt][0] * rinv, p[rt][1] * rinv);
      wpk[rt][1] = pack2(p[rt][2] * rinv, p[rt][3] * rinv);
    }
    bf16x8 bp1 = xpose(wpk[0][0], wpk[0][1], wpk[1][0], wpk[1][1], s0, s1, hiSel);
    bf16x8 bp2 = xpose(wpk[2][0], wpk[2][1], wpk[3][0], wpk[3][1], s0, s1, hiSel);

    // o^T = mfma(V^T, P^T) -> pack -> of[h] in registers
    uint32_t uo[2][2];
    #pragma unroll
    for (int ct2 = 0; ct2 < 2; ++ct2) {
      const short* vb = vth + (16 * ct2 + l16) * VROW;
      bf16x8 bv1 = *reinterpret_cast<const bf16x8*>(vb + g4 * 8);
      bf16x8 bv2 = *reinterpret_cast<const bf16x8*>(vb + 32 + g4 * 8);
      f32x4 acc = {0.f, 0.f, 0.f, 0.f};
      acc = __builtin_amdgcn_mfma_f32_16x16x32_bf16(bv1, bp1, acc, 0, 0, 0);
      acc = __builtin_amdgcn_mfma_f32_16x16x32_bf16(bv2, bp2, acc, 0, 0, 0);
      uo[ct2][0] = pack2(acc[0], acc[1]);
      uo[ct2][1] = pack2(acc[2], acc[3]);
    }
    of[h] = xpose(uo[0][0], uo[0][1], uo[1][0], uo[1][1], s0, s1, hiSel);
  }

  // ---- proj: 3 chunks of 64 cols, of[] as A-operand ----
  float* og = out + (size_t)b * (NTOK * CDIM);
  #pragma unroll
  for (int c = 0; c < 3; ++c) {
    __syncthreads();                         // prior wbuf readers done
    stage64(wbuf, wsp + (size_t)(64 * c) * CDIM, tid);
    __syncthreads();
    #pragma unroll
    for (int lct = 0; lct < 4; ++lct) {
      f32x4 acc = {0.f, 0.f, 0.f, 0.f};
      #pragma unroll
      for (int ks = 0; ks < 6; ++ks) {
        bf16x8 wf = *reinterpret_cast<const bf16x8*>(wbuf + (lct * 16 + l16) * LROW + ks * 32 + g4 * 8);
        acc = __builtin_amdgcn_mfma_f32_16x16x32_bf16(of[ks], wf, acc, 0, 0, 0);
      }
      const int cc = 64 * c + 16 * lct + l16;
      const float pb = proj_b[cc];
      #pragma unroll
      for (int i = 0; i < 4; ++i)
        og[(m0 + 4 * g4 + i) * CDIM + cc] = acc[i] + pb;
    }
  }
}

extern "C" void kernel_launch(void* const* d_in, const int* in_sizes, int n_in,
                              void* d_out, int out_size, void* d_ws, size_t ws_size,
                              hipStream_t stream) {
  const float* x      = (const float*)d_in[0];
  const float* mask   = (const float*)d_in[1];
  const float* qkv_w  = (const float*)d_in[2];
  const float* qkv_b  = (const float*)d_in[3];
  const float* proj_w = (const float*)d_in[4];
  const float* proj_b = (const float*)d_in[5];
  float* out = (float*)d_out;

  short* wsq = (short*)d_ws;             // [576][192] bf16
  short* wsp = wsq + 576 * CDIM;         // [192][192] bf16

  wconv_kernel<<<768, 192, 0, stream>>>(qkv_w, proj_w, wsq, wsp);
  winattn_kernel<<<4096, 256, 0, stream>>>(x, mask, wsq, wsp, qkv_b, proj_b, out);
}

// Round 4
// 219.963 us; speedup vs baseline: 2.9110x; 1.2429x over previous
//
#include <hip/hip_runtime.h>
#include <stdint.h>

// WindowAttention: B_=4096 windows, N=64 tokens, C=192, H=6 heads, hd=32.
// One block per window, 4 waves. bf16 MFMA 16x16x32, fp32 accum.
// Round 4: weights staged via global_load_lds from a PRE-SWIZZLED workspace
// (linear LDS dest + inverse-swizzled global source + swizzled read), loads
// issued one phase early so L2 latency hides under compute. Mask hoisted.

#define NTOK 64
#define CDIM 192
#define KROW 40           // kh row stride (shorts): 80 B
#define VROW 72           // vth row stride (shorts): 144 B

// workspace layout (shorts): Wq 3x(64x192) | per-head Wk(32x192)+Wv(32x192) | Wp 3x(64x192)
#define WS_KV 36864
#define WS_P  110592

typedef __attribute__((ext_vector_type(4))) float f32x4;
typedef __attribute__((ext_vector_type(8))) short bf16x8;

__device__ __forceinline__ short f2bf(float f) {
  union { float f; uint32_t u; } v; v.f = f;
  return (short)(uint16_t)((v.u + 0x7FFFu + ((v.u >> 16) & 1u)) >> 16);  // RNE
}
__device__ __forceinline__ uint32_t pack2(float a, float b) {
  return (uint32_t)(uint16_t)f2bf(a) | ((uint32_t)(uint16_t)f2bf(b) << 16);
}

// Cross-lane transpose (validated round 2/3): build bf16x8 fragment via shfl.
__device__ __forceinline__ bf16x8 xpose(uint32_t A0, uint32_t A1,
                                        uint32_t B0, uint32_t B1,
                                        int s0, int s1, int hiSel) {
  uint32_t w[4];
  uint32_t a, b;
  a = (uint32_t)__shfl((int)A0, s0); b = (uint32_t)__shfl((int)B0, s0); w[0] = hiSel ? b : a;
  a = (uint32_t)__shfl((int)A1, s0); b = (uint32_t)__shfl((int)B1, s0); w[1] = hiSel ? b : a;
  a = (uint32_t)__shfl((int)A0, s1); b = (uint32_t)__shfl((int)B0, s1); w[2] = hiSel ? b : a;
  a = (uint32_t)__shfl((int)A1, s1); b = (uint32_t)__shfl((int)B1, s1); w[3] = hiSel ? b : a;
  return *reinterpret_cast<bf16x8*>(w);
}

#define GLOAD16(g, l) __builtin_amdgcn_global_load_lds( \
    (const __attribute__((address_space(1))) void*)(g), \
    (__attribute__((address_space(3))) void*)(l), 16, 0, 0)

// Pre-convert + pre-swizzle weights fp32 -> bf16 into ws.
// Slot swizzle within each 64-row chunk: s' = (s&24) | ((s^row)&7), 16B slots.
__global__ void wconv_kernel(const float* __restrict__ qkv_w,
                             const float* __restrict__ proj_w,
                             short* __restrict__ ws) {
  const int r = blockIdx.x, c = threadIdx.x;   // 768 x 192
  float val;
  int base, lr;
  if (r < 192) {                               // Wq: 3 chunks of 64 rows
    base = (r >> 6) * 12288; lr = r & 63;
    val = qkv_w[r * CDIM + c];
  } else if (r < 576) {                        // Wk/Wv per head: 32 rows each
    const int rr = r - 192;                    // 0..383 (k: 0..191, v: 192..383)
    const int h = (rr % 192) >> 5;
    lr = rr & 31;
    base = WS_KV + h * 12288 + ((rr < 192) ? 0 : 6144);
    val = qkv_w[r * CDIM + c];
  } else {                                     // Wp: 3 chunks of 64 rows
    const int rr = r - 576;
    base = WS_P + (rr >> 6) * 12288; lr = rr & 63;
    val = proj_w[rr * CDIM + c];
  }
  const int s = c >> 3, lo = c & 7;
  const int sp = (s & 24) | ((s ^ lr) & 7);
  ws[base + lr * CDIM + sp * 8 + lo] = f2bf(val);
}

// Issue 24KB chunk: global (pre-swizzled) -> LDS linear, no VGPR round-trip.
__device__ __forceinline__ void stage_issue(short* __restrict__ wbuf,
                                            const short* __restrict__ src, int tid) {
  const int w = tid >> 6, lane = tid & 63;
  #pragma unroll
  for (int it = 0; it < 6; ++it) {
    const int cidx = it * 4 + w;               // wave-uniform 1KB chunk id
    GLOAD16(src + cidx * 512 + lane * 8, wbuf + cidx * 512);
  }
}

__global__ __launch_bounds__(256, 4)
void winattn_kernel(const float* __restrict__ x, const float* __restrict__ mask,
                    const short* __restrict__ ws,
                    const float* __restrict__ qkv_b, const float* __restrict__ proj_b,
                    float* __restrict__ out) {
  __shared__ __align__(16) short wbuf[64 * CDIM];   // linear [64][192], swizzled content
  __shared__ __align__(16) short kh[NTOK * KROW];   // current head k [tok][32]
  __shared__ __align__(16) short vth[32 * VROW];    // current head v^T [ch][tok]

  const int b    = blockIdx.x;
  const int tid  = threadIdx.x;
  const int lane = tid & 63;
  const int l16  = lane & 15;
  const int g4   = lane >> 4;
  const int m0   = (tid >> 6) * 16;
  const float scale = 0.17677669529663687f;  // 32^-0.5
  const int s0 = (((2 * g4) & 3) << 4) + l16;
  const int s1 = (((2 * g4 + 1) & 3) << 4) + l16;
  const int hiSel = g4 >> 1;

  // per-lane swizzled slot offsets (shorts): row&7 == l16&7 for all phases
  int soff[6];
  #pragma unroll
  for (int ks = 0; ks < 6; ++ks) {
    const int s = ks * 4 + g4;
    soff[ks] = ((s & 24) | ((s ^ l16) & 7)) << 3;
  }

  // ---- prologue: kick off Q-chunk-0 staging, then x->af and mask hoist ----
  stage_issue(wbuf, ws, tid);

  const float* xr = x + (size_t)b * (NTOK * CDIM) + (m0 + l16) * CDIM;
  bf16x8 af[6];
  #pragma unroll
  for (int ks = 0; ks < 6; ++ks) {
    const float4 v0 = *reinterpret_cast<const float4*>(xr + ks * 32 + g4 * 8);
    const float4 v1 = *reinterpret_cast<const float4*>(xr + ks * 32 + g4 * 8 + 4);
    bf16x8 t;
    t[0] = f2bf(v0.x); t[1] = f2bf(v0.y); t[2] = f2bf(v0.z); t[3] = f2bf(v0.w);
    t[4] = f2bf(v1.x); t[5] = f2bf(v1.y); t[6] = f2bf(v1.z); t[7] = f2bf(v1.w);
    af[ks] = t;
  }
  const float* mrowl = mask + (size_t)b * (NTOK * NTOK) + (m0 + l16) * NTOK;
  float4 mreg[4];
  #pragma unroll
  for (int rt = 0; rt < 4; ++rt)
    mreg[rt] = *reinterpret_cast<const float4*>(mrowl + 16 * rt + 4 * g4);

  __syncthreads();                             // Q0 resident

  // ---- q phase: q^T = mfma(Wq, x) -> aq[] in registers ----
  bf16x8 aq[6];
  #pragma unroll
  for (int c = 0; c < 3; ++c) {
    uint32_t u[4][2];
    #pragma unroll
    for (int lct = 0; lct < 4; ++lct) {
      f32x4 acc = {0.f, 0.f, 0.f, 0.f};
      #pragma unroll
      for (int ks = 0; ks < 6; ++ks) {
        bf16x8 wf = *reinterpret_cast<const bf16x8*>(wbuf + (lct * 16 + l16) * CDIM + soff[ks]);
        acc = __builtin_amdgcn_mfma_f32_16x16x32_bf16(wf, af[ks], acc, 0, 0, 0);
      }
      const float4 bq = *reinterpret_cast<const float4*>(qkv_b + 64 * c + 16 * lct + 4 * g4);
      u[lct][0] = pack2((acc[0] + bq.x) * scale, (acc[1] + bq.y) * scale);
      u[lct][1] = pack2((acc[2] + bq.z) * scale, (acc[3] + bq.w) * scale);
    }
    __syncthreads();                           // wbuf readers done (all waves)
    stage_issue(wbuf, ws + (c < 2 ? (c + 1) * 12288 : WS_KV), tid);
    aq[2 * c]     = xpose(u[0][0], u[0][1], u[1][0], u[1][1], s0, s1, hiSel);
    aq[2 * c + 1] = xpose(u[2][0], u[2][1], u[3][0], u[3][1], s0, s1, hiSel);
    __syncthreads();                           // drains vmcnt -> next chunk resident
  }

  // ---- per-head loop: wbuf holds [Wk_h (rows 0..31) | Wv_h (rows 32..63)] ----
  bf16x8 of[6];
  #pragma unroll
  for (int h = 0; h < 6; ++h) {
    // k^T = mfma(Wk, x) -> kh[tok][ch]
    #pragma unroll
    for (int lct = 0; lct < 2; ++lct) {
      f32x4 acc = {0.f, 0.f, 0.f, 0.f};
      #pragma unroll
      for (int ks = 0; ks < 6; ++ks) {
        bf16x8 wf = *reinterpret_cast<const bf16x8*>(wbuf + (lct * 16 + l16) * CDIM + soff[ks]);
        acc = __builtin_amdgcn_mfma_f32_16x16x32_bf16(wf, af[ks], acc, 0, 0, 0);
      }
      const float4 bk4 = *reinterpret_cast<const float4*>(qkv_b + 192 + 32 * h + 16 * lct + 4 * g4);
      uint2 kw;
      kw.x = pack2(acc[0] + bk4.x, acc[1] + bk4.y);
      kw.y = pack2(acc[2] + bk4.z, acc[3] + bk4.w);
      *reinterpret_cast<uint2*>(kh + (m0 + l16) * KROW + 16 * lct + 4 * g4) = kw;
    }
    // v = mfma(x, Wv) -> vth[ch][tok]
    #pragma unroll
    for (int lct = 0; lct < 2; ++lct) {
      f32x4 acc = {0.f, 0.f, 0.f, 0.f};
      #pragma unroll
      for (int ks = 0; ks < 6; ++ks) {
        bf16x8 wf = *reinterpret_cast<const bf16x8*>(wbuf + (32 + lct * 16 + l16) * CDIM + soff[ks]);
        acc = __builtin_amdgcn_mfma_f32_16x16x32_bf16(af[ks], wf, acc, 0, 0, 0);
      }
      const float bv = qkv_b[384 + 32 * h + 16 * lct + l16];
      uint2 vw;
      vw.x = pack2(acc[0] + bv, acc[1] + bv);
      vw.y = pack2(acc[2] + bv, acc[3] + bv);
      *reinterpret_cast<uint2*>(vth + (16 * lct + l16) * VROW + m0 + 4 * g4) = vw;
    }
    __syncthreads();                           // kh/vth ready; wbuf readers done
    stage_issue(wbuf, ws + (h < 5 ? WS_KV + (h + 1) * 12288 : WS_P), tid);

    // S^T = mfma(K, q) + mask; softmax in-register (lane owns one q-row)
    float p[4][4];
    float rmax = -1e30f;
    #pragma unroll
    for (int rt = 0; rt < 4; ++rt) {
      bf16x8 bk = *reinterpret_cast<const bf16x8*>(kh + (rt * 16 + l16) * KROW + g4 * 8);
      f32x4 z = {0.f, 0.f, 0.f, 0.f};
      f32x4 s = __builtin_amdgcn_mfma_f32_16x16x32_bf16(bk, aq[h], z, 0, 0, 0);
      p[rt][0] = s[0] + mreg[rt].x; p[rt][1] = s[1] + mreg[rt].y;
      p[rt][2] = s[2] + mreg[rt].z; p[rt][3] = s[3] + mreg[rt].w;
      #pragma unroll
      for (int i = 0; i < 4; ++i) rmax = fmaxf(rmax, p[rt][i]);
    }
    rmax = fmaxf(rmax, __shfl_xor(rmax, 16));
    rmax = fmaxf(rmax, __shfl_xor(rmax, 32));
    float rsum = 0.f;
    #pragma unroll
    for (int rt = 0; rt < 4; ++rt)
      #pragma unroll
      for (int i = 0; i < 4; ++i) { p[rt][i] = __expf(p[rt][i] - rmax); rsum += p[rt][i]; }
    rsum += __shfl_xor(rsum, 16);
    rsum += __shfl_xor(rsum, 32);
    const float rinv = 1.f / rsum;

    uint32_t wpk[4][2];
    #pragma unroll
    for (int rt = 0; rt < 4; ++rt) {
      wpk[rt][0] = pack2(p[rt][0] * rinv, p[rt][1] * rinv);
      wpk[rt][1] = pack2(p[rt][2] * rinv, p[rt][3] * rinv);
    }
    bf16x8 bp1 = xpose(wpk[0][0], wpk[0][1], wpk[1][0], wpk[1][1], s0, s1, hiSel);
    bf16x8 bp2 = xpose(wpk[2][0], wpk[2][1], wpk[3][0], wpk[3][1], s0, s1, hiSel);

    // o^T = mfma(V^T, P^T) -> of[h]
    uint32_t uo[2][2];
    #pragma unroll
    for (int ct2 = 0; ct2 < 2; ++ct2) {
      const short* vb = vth + (16 * ct2 + l16) * VROW;
      bf16x8 bv1 = *reinterpret_cast<const bf16x8*>(vb + g4 * 8);
      bf16x8 bv2 = *reinterpret_cast<const bf16x8*>(vb + 32 + g4 * 8);
      f32x4 acc = {0.f, 0.f, 0.f, 0.f};
      acc = __builtin_amdgcn_mfma_f32_16x16x32_bf16(bv1, bp1, acc, 0, 0, 0);
      acc = __builtin_amdgcn_mfma_f32_16x16x32_bf16(bv2, bp2, acc, 0, 0, 0);
      uo[ct2][0] = pack2(acc[0], acc[1]);
      uo[ct2][1] = pack2(acc[2], acc[3]);
    }
    of[h] = xpose(uo[0][0], uo[0][1], uo[1][0], uo[1][1], s0, s1, hiSel);

    __syncthreads();                           // next wbuf resident; kh/vth reads done
  }

  // ---- proj: 3 chunks, of[] as A-operand; stores hide next-chunk latency ----
  float* og = out + (size_t)b * (NTOK * CDIM);
  #pragma unroll
  for (int c = 0; c < 3; ++c) {
    f32x4 acc[4];
    #pragma unroll
    for (int lct = 0; lct < 4; ++lct) {
      f32x4 a = {0.f, 0.f, 0.f, 0.f};
      #pragma unroll
      for (int ks = 0; ks < 6; ++ks) {
        bf16x8 wf = *reinterpret_cast<const bf16x8*>(wbuf + (lct * 16 + l16) * CDIM + soff[ks]);
        a = __builtin_amdgcn_mfma_f32_16x16x32_bf16(of[ks], wf, a, 0, 0, 0);
      }
      acc[lct] = a;
    }
    if (c < 2) {
      __syncthreads();                         // wbuf readers done
      stage_issue(wbuf, ws + WS_P + (c + 1) * 12288, tid);
    }
    #pragma unroll
    for (int lct = 0; lct < 4; ++lct) {
      const int cc = 64 * c + 16 * lct + l16;
      const float pb = proj_b[cc];
      #pragma unroll
      for (int i = 0; i < 4; ++i)
        og[(m0 + 4 * g4 + i) * CDIM + cc] = acc[lct][i] + pb;
    }
    if (c < 2) __syncthreads();                // next chunk resident
  }
}

extern "C" void kernel_launch(void* const* d_in, const int* in_sizes, int n_in,
                              void* d_out, int out_size, void* d_ws, size_t ws_size,
                              hipStream_t stream) {
  const float* x      = (const float*)d_in[0];
  const float* mask   = (const float*)d_in[1];
  const float* qkv_w  = (const float*)d_in[2];
  const float* qkv_b  = (const float*)d_in[3];
  const float* proj_w = (const float*)d_in[4];
  const float* proj_b = (const float*)d_in[5];
  float* out = (float*)d_out;

  short* ws = (short*)d_ws;                    // 147456 shorts = 294912 B

  wconv_kernel<<<768, 192, 0, stream>>>(qkv_w, proj_w, ws);
  winattn_kernel<<<4096, 256, 0, stream>>>(x, mask, ws, qkv_b, proj_b, out);
}